// Round 8
// baseline (387.643 us; speedup 1.0000x reference)
//
#include <hip/hip_runtime.h>
#include <cstdint>

typedef unsigned short u16;
typedef __attribute__((ext_vector_type(8))) short s16x8;
typedef __attribute__((ext_vector_type(4))) float f32x4;
typedef __attribute__((ext_vector_type(8))) unsigned short u16x8;
typedef __attribute__((ext_vector_type(4))) unsigned short u16x4;

#define B_ 128
#define T_ 512
#define C_ 512
#define TC 262144

static __device__ __forceinline__ float bf2f(u16 u) {
  union { unsigned int i; float f; } v; v.i = ((unsigned int)u) << 16; return v.f;
}
static __device__ __forceinline__ u16 f2bf(float f) {
  union { float fv; unsigned int i; } v; v.fv = f;
  unsigned int r = (v.i + 0x7FFFu + ((v.i >> 16) & 1u)) >> 16;
  return (u16)r;
}

// x*sigmoid(2z) form of tanh-GELU (passed with absmax 0.031).
static __device__ __forceinline__ float gelu_fast(float x) {
  float x2 = x * x;
  float arg = 1.5957691216057308f * x * fmaf(0.044715f, x2, 1.0f);
  return x / (1.0f + __expf(-arg));
}

#define GLD16(gp, lp) __builtin_amdgcn_global_load_lds( \
    (const __attribute__((address_space(1))) void*)(gp), \
    (__attribute__((address_space(3))) void*)(lp), 16, 0, 0)

// ---------------- LN1 stats: two-stage deterministic reduction ----------------

__global__ __launch_bounds__(256)
void reduce_stats_kernel(const float* __restrict__ X, float2* __restrict__ partials) {
  const int b = blockIdx.y, blk = blockIdx.x, tid = threadIdx.x;
  const float* p = X + (size_t)b * TC + (size_t)blk * 2048 + (size_t)tid * 8;
  f32x4 v0 = *(const f32x4*)p;
  f32x4 v1 = *(const f32x4*)(p + 4);
  float s = 0.f, q = 0.f;
#pragma unroll
  for (int i = 0; i < 4; ++i) { s += v0[i] + v1[i]; q += v0[i] * v0[i] + v1[i] * v1[i]; }
  for (int o = 32; o; o >>= 1) { s += __shfl_down(s, o); q += __shfl_down(q, o); }
  __shared__ float ss[4], qq[4];
  if ((tid & 63) == 0) { ss[tid >> 6] = s; qq[tid >> 6] = q; }
  __syncthreads();
  if (tid == 0)
    partials[(size_t)b * 128 + blk] =
        make_float2(ss[0] + ss[1] + ss[2] + ss[3], qq[0] + qq[1] + qq[2] + qq[3]);
}

__global__ __launch_bounds__(128)
void finalize_stats_kernel(const float2* __restrict__ partials, float2* __restrict__ stats) {
  const int b = blockIdx.x, tid = threadIdx.x;
  float2 v = partials[(size_t)b * 128 + tid];
  float s = v.x, q = v.y;
  for (int o = 32; o; o >>= 1) { s += __shfl_down(s, o); q += __shfl_down(q, o); }
  __shared__ float ss[2], qq[2];
  if ((tid & 63) == 0) { ss[tid >> 6] = s; qq[tid >> 6] = q; }
  __syncthreads();
  if (tid == 0) {
    float sm = ss[0] + ss[1], sq = qq[0] + qq[1];
    float mean = sm * (1.f / (float)TC);
    float var = sq * (1.f / (float)TC) - mean * mean;
    stats[b] = make_float2(mean, rsqrtf(var + 1e-5f));
  }
}

// finalize for 16 partials per batch (TriU-epilogue fused LN2 stats, 128^2 tiles)
__global__ __launch_bounds__(64)
void finalize_stats16_kernel(const float2* __restrict__ partials, float2* __restrict__ stats) {
  const int b = blockIdx.x, tid = threadIdx.x;
  float s = 0.f, q = 0.f;
  if (tid < 16) { float2 v = partials[(size_t)b * 16 + tid]; s = v.x; q = v.y; }
  for (int o = 8; o; o >>= 1) { s += __shfl_down(s, o); q += __shfl_down(q, o); }
  if (tid == 0) {
    float mean = s * (1.f / (float)TC);
    float var = q * (1.f / (float)TC) - mean * mean;
    stats[b] = make_float2(mean, rsqrtf(var + 1e-5f));
  }
}

// --------- LN1 apply + transpose: x^T[b][c][t] = bf16(LN(inputs)) ----------

__global__ __launch_bounds__(256)
void ln1_transpose_kernel(const float* __restrict__ X, const float* __restrict__ W,
                          const float* __restrict__ Bv, const float2* __restrict__ stats,
                          u16* __restrict__ xT) {
  const int b = blockIdx.z;
  const int t0 = blockIdx.y * 64, c0 = blockIdx.x * 64;
  const float2 st = stats[b];
  const float mu = st.x, rs = st.y;
  __shared__ u16 tile[64][72];
  const int tid = threadIdx.x;
  const int rr = tid >> 4;
  const int cc = (tid & 15) * 4;
#pragma unroll
  for (int i = 0; i < 4; ++i) {
    const int lt = i * 16 + rr;
    const size_t wi = (size_t)(t0 + lt) * C_ + c0 + cc;
    f32x4 x = *(const f32x4*)(X + (size_t)b * TC + wi);
    f32x4 w = *(const f32x4*)(W + wi);
    f32x4 bb = *(const f32x4*)(Bv + wi);
#pragma unroll
    for (int j = 0; j < 4; ++j)
      tile[lt][cc + j] = f2bf((x[j] - mu) * rs * w[j] + bb[j]);
  }
  __syncthreads();
  const int c = tid >> 2;
  const int tg = (tid & 3) * 16;
  u16 buf[16];
#pragma unroll
  for (int i = 0; i < 16; ++i) buf[i] = tile[tg + i][c];
  const size_t o = (size_t)b * TC + (size_t)(c0 + c) * T_ + t0 + tg;
  u16x8 o0, o1;
#pragma unroll
  for (int i = 0; i < 8; ++i) { o0[i] = buf[i]; o1[i] = buf[8 + i]; }
  *(u16x8*)(xT + o) = o0;
  *(u16x8*)(xT + o + 8) = o1;
}

// ------------------- LN2 apply (elementwise, bf16 input) -------------------

__global__ __launch_bounds__(256)
void ln2_apply_kernel(const u16* __restrict__ S, const float* __restrict__ W,
                      const float* __restrict__ Bv, const float2* __restrict__ stats,
                      u16* __restrict__ x2) {
  const size_t i = ((size_t)blockIdx.x * 256 + threadIdx.x) * 8;
  const int b = (int)(i >> 18);
  const size_t r = i & (size_t)(TC - 1);
  const float2 st = stats[b];
  const float mu = st.x, rs = st.y;
  u16x8 sv = *(const u16x8*)(S + i);
  f32x4 w0 = *(const f32x4*)(W + r);
  f32x4 w1 = *(const f32x4*)(W + r + 4);
  f32x4 b0 = *(const f32x4*)(Bv + r);
  f32x4 b1 = *(const f32x4*)(Bv + r + 4);
  u16x8 o;
#pragma unroll
  for (int j = 0; j < 4; ++j) {
    o[j]     = f2bf((bf2f(sv[j])     - mu) * rs * w0[j] + b0[j]);
    o[4 + j] = f2bf((bf2f(sv[4 + j]) - mu) * rs * w1[j] + b1[j]);
  }
  *(u16x8*)(x2 + i) = o;
}

// --------------------------- weight conversions ----------------------------

__global__ __launch_bounds__(256)
void cvt_bf16_kernel(const float* __restrict__ X, u16* __restrict__ Y) {
  const size_t i = ((size_t)blockIdx.x * 256 + threadIdx.x) * 4;
  f32x4 v = *(const f32x4*)(X + i);
  u16x4 o;
#pragma unroll
  for (int j = 0; j < 4; ++j) o[j] = f2bf(v[j]);
  *(u16x4*)(Y + i) = o;
}

__global__ __launch_bounds__(256)
void tril_bf16_kernel(const float* __restrict__ Wt, u16* __restrict__ Y) {
  const int i = blockIdx.x * 256 + threadIdx.x;
  const int s = i >> 9, t = i & 511;
  Y[i] = f2bf(t <= s ? Wt[i] : 0.f);
}

// ----------- BT-layout MFMA GEMM, 128x128 tile, BK=64, 2 blocks/CU ----------
// C[m,n] = sum_k A[m,k]*B[n,k].  BM=BN=128, BK=64, 256 thr = 4 waves (2x2),
// per-wave 64x64 C (4x4 frags of 16x16x32).  LDS 64KB (A/B dbuf) -> 2
// blocks/CU: independent blocks overlap each other's barrier/drain stalls
// (m97 mechanism — TLP instead of source pipelining, which is null on
// 2-phase structures).  XOR-swizzled staging (proven, 0 bank conflicts):
// source col-chunk ^ (row&7), LDS dest linear, ds_read applies same XOR.
// MODE 0: TriU  (z-batched; C=bf16 s = acc+inputs+triu_b[row]; tri K-skip;
//               fused per-block LN2 partial stats)
// MODE 1: fc1   (C=bf16 h = gelu(acc + fc1_b[col]))
// MODE 2: fc2   (C=fp32 out = acc + fc2_b[col] + x2[idx])

template <int MODE>
__global__ __launch_bounds__(256, 2)
void gemm_bt_kernel(const u16* __restrict__ A, const u16* __restrict__ Bm,
                    int K, int lda, int ldb,
                    void* __restrict__ Cp, int ldc,
                    const float* __restrict__ bias,
                    const void* __restrict__ res,
                    long long strideB, long long strideC,
                    float2* __restrict__ stat_part) {
  __shared__ u16 Asb[2 * 8192];   // [dbuf][128 rows][64 k]  (32 KiB)
  __shared__ u16 Bsb[2 * 8192];   // [dbuf][128 rows][64 k]  (32 KiB)
  __shared__ float rs_[4], rq_[4];
  const int tid = threadIdx.x;

  // --- XCD-aware bijective remap (nwg % 8 == 0 for all launches) ---
  const int nwg = gridDim.x;
  const int orig = blockIdx.x;
  const int swz = (orig & 7) * (nwg >> 3) + (orig >> 3);
  int bx, by, bz;
  if (MODE == 0) { bz = swz >> 4; by = (swz >> 2) & 3; bx = swz & 3; }
  else if (MODE == 1) { bz = 0; by = swz >> 3; bx = swz & 7; }
  else { bz = 0; by = swz >> 2; bx = swz & 3; }

  const u16* Bp = Bm + (size_t)bz * (size_t)strideB;
  const int m0 = by * 128, n0 = bx * 128;
  int kTiles = K >> 6;
  if (MODE == 0) { const int need = (by + 1) * 2; if (need < kTiles) kTiles = need; }

  const int lane = tid & 63;
  const int wave = tid >> 6;
  const int wm = (wave >> 1) * 64;
  const int wn = (wave & 1) * 64;
  const int lr = lane & 15;
  const int kg = lane >> 4;

  f32x4 acc[4][4];
  const f32x4 zero = {0.f, 0.f, 0.f, 0.f};
#pragma unroll
  for (int m = 0; m < 4; ++m)
#pragma unroll
    for (int n = 0; n < 4; ++n) acc[m][n] = zero;

  // One operand tile = 128 rows x 128B = 1024 16B-chunks = 4 GLD16/thread.
  auto STAGE = [&](int buf, int kt) {
    const int k0 = kt << 6;
    const int d = buf * 8192;
#pragma unroll
    for (int p = 0; p < 4; ++p) {
      const int q = p * 256 + tid;
      const int r = q >> 3;
      const int kcs = (q & 7) ^ (r & 7);
      GLD16(A + (size_t)(m0 + r) * lda + k0 + (kcs << 3), &Asb[d + q * 8]);
    }
#pragma unroll
    for (int p = 0; p < 4; ++p) {
      const int q = p * 256 + tid;
      const int r = q >> 3;
      const int kcs = (q & 7) ^ (r & 7);
      GLD16(Bp + (size_t)(n0 + r) * ldb + k0 + (kcs << 3), &Bsb[d + q * 8]);
    }
  };

  STAGE(0, 0);
  int cur = 0;
  for (int kt = 0; kt < kTiles; ++kt) {
    __syncthreads();                      // buf[cur] landed; prior reads done
    if (kt + 1 < kTiles) STAGE(cur ^ 1, kt + 1);   // overlaps MFMA below
#pragma unroll
    for (int kk = 0; kk < 2; ++kk) {
      s16x8 af[4], bfv[4];
#pragma unroll
      for (int m = 0; m < 4; ++m) {
        const int row = wm + m * 16 + lr;
        af[m] = *(const s16x8*)&Asb[cur * 8192 + row * 64 + (((kk * 4 + kg) ^ (row & 7)) << 3)];
      }
#pragma unroll
      for (int n = 0; n < 4; ++n) {
        const int row = wn + n * 16 + lr;
        bfv[n] = *(const s16x8*)&Bsb[cur * 8192 + row * 64 + (((kk * 4 + kg) ^ (row & 7)) << 3)];
      }
#pragma unroll
      for (int m = 0; m < 4; ++m)
#pragma unroll
        for (int n = 0; n < 4; ++n)
          acc[m][n] = __builtin_amdgcn_mfma_f32_16x16x32_bf16(af[m], bfv[n], acc[m][n], 0, 0, 0);
    }
    cur ^= 1;
  }

  if (MODE == 0) {
    u16* Cptr = (u16*)Cp + (size_t)bz * (size_t)strideC;
    const float* inp = (const float*)res + (size_t)bz * (size_t)strideC;
    float psum = 0.f, psq = 0.f;
#pragma unroll
    for (int m = 0; m < 4; ++m) {
      const int rb = m0 + wm + m * 16 + kg * 4;
#pragma unroll
      for (int n = 0; n < 4; ++n) {
        const int col = n0 + wn + n * 16 + lr;
#pragma unroll
        for (int j = 0; j < 4; ++j) {
          const size_t idx = (size_t)(rb + j) * ldc + col;
          float v = acc[m][n][j] + inp[idx] + bias[rb + j];
          psum += v; psq += v * v;
          Cptr[idx] = f2bf(v);
        }
      }
    }
    for (int o = 32; o; o >>= 1) { psum += __shfl_down(psum, o); psq += __shfl_down(psq, o); }
    if (lane == 0) { rs_[wave] = psum; rq_[wave] = psq; }
    __syncthreads();
    if (tid == 0)
      stat_part[(size_t)bz * 16 + by * 4 + bx] =
          make_float2(rs_[0] + rs_[1] + rs_[2] + rs_[3], rq_[0] + rq_[1] + rq_[2] + rq_[3]);
  } else if (MODE == 1) {
    u16* Cptr = (u16*)Cp;
#pragma unroll
    for (int m = 0; m < 4; ++m) {
      const int rb = m0 + wm + m * 16 + kg * 4;
#pragma unroll
      for (int n = 0; n < 4; ++n) {
        const int col = n0 + wn + n * 16 + lr;
        const float bs = bias[col];
#pragma unroll
        for (int j = 0; j < 4; ++j) {
          float v = acc[m][n][j] + bs;
          Cptr[(size_t)(rb + j) * ldc + col] = f2bf(gelu_fast(v));
        }
      }
    }
  } else {
    float* Cptr = (float*)Cp;
    const u16* x2p = (const u16*)res;
#pragma unroll
    for (int m = 0; m < 4; ++m) {
      const int rb = m0 + wm + m * 16 + kg * 4;
#pragma unroll
      for (int n = 0; n < 4; ++n) {
        const int col = n0 + wn + n * 16 + lr;
        const float bs = bias[col];
#pragma unroll
        for (int j = 0; j < 4; ++j) {
          const size_t idx = (size_t)(rb + j) * ldc + col;
          Cptr[idx] = acc[m][n][j] + bs + bf2f(x2p[idx]);
        }
      }
    }
  }
}

// -------------------------------- launcher ---------------------------------

extern "C" void kernel_launch(void* const* d_in, const int* in_sizes, int n_in,
                              void* d_out, int out_size, void* d_ws, size_t ws_size,
                              hipStream_t stream) {
  const float* inputs = (const float*)d_in[0];
  const float* ln1_w  = (const float*)d_in[1];
  const float* ln1_b  = (const float*)d_in[2];
  const float* ln2_w  = (const float*)d_in[3];
  const float* ln2_b  = (const float*)d_in[4];
  const float* triu_W = (const float*)d_in[5];
  const float* triu_b = (const float*)d_in[6];
  const float* fc1_W  = (const float*)d_in[7];
  const float* fc1_b  = (const float*)d_in[8];
  const float* fc2_W  = (const float*)d_in[9];
  const float* fc2_b  = (const float*)d_in[10];
  float* out = (float*)d_out;
  (void)in_sizes; (void)n_in; (void)out_size; (void)ws_size;

  char* ws = (char*)d_ws;
  size_t off = 0;
  auto carve = [&](size_t bytes) {
    char* p = ws + off;
    off += (bytes + 255) & ~(size_t)255;
    return p;
  };
  u16* s_bf = (u16*)carve((size_t)B_ * T_ * C_ * 2);   // 67MB bf16 s = mix+inputs+bias
  u16* xT   = (u16*)carve((size_t)B_ * T_ * C_ * 2);   // 67MB; reused as x2
  u16* x2   = xT;
  u16* h    = (u16*)carve((size_t)B_ * T_ * 2 * C_ * 2); // 134MB bf16
  u16* wmb  = (u16*)carve((size_t)T_ * T_ * 2);
  u16* w1b  = (u16*)carve((size_t)2 * C_ * C_ * 2);
  u16* w2b  = (u16*)carve((size_t)C_ * 2 * C_ * 2);
  float2* partials  = (float2*)carve(128 * 128 * sizeof(float2));
  float2* partials2 = (float2*)carve(128 * 16 * sizeof(float2));
  float2* stats1 = (float2*)carve(128 * sizeof(float2));
  float2* stats2 = (float2*)carve(128 * sizeof(float2));

  // LN1 stats
  reduce_stats_kernel<<<dim3(128, 128), 256, 0, stream>>>(inputs, partials);
  finalize_stats_kernel<<<128, 128, 0, stream>>>(partials, stats1);
  // LN1 apply + transpose -> xT (bf16)
  ln1_transpose_kernel<<<dim3(8, 8, 128), 256, 0, stream>>>(inputs, ln1_w, ln1_b, stats1, xT);
  // weight prep
  tril_bf16_kernel<<<1024, 256, 0, stream>>>(triu_W, wmb);
  cvt_bf16_kernel<<<512, 256, 0, stream>>>(fc1_W, w1b);
  cvt_bf16_kernel<<<512, 256, 0, stream>>>(fc2_W, w2b);
  // TriU mix: s = tril(W) @ x + triu_b + inputs (bf16 out) + fused LN2 partial stats
  gemm_bt_kernel<0><<<2048, 256, 0, stream>>>(
      wmb, xT, 512, 512, 512, s_bf, 512, triu_b, inputs, (long long)TC, (long long)TC, partials2);
  finalize_stats16_kernel<<<128, 64, 0, stream>>>(partials2, stats2);
  // LN2 apply -> x2 (bf16)
  ln2_apply_kernel<<<16384, 256, 0, stream>>>(s_bf, ln2_w, ln2_b, stats2, x2);
  // fc1 + GELU -> h (bf16)
  gemm_bt_kernel<1><<<4096, 256, 0, stream>>>(
      x2, w1b, 512, 512, 512, h, 1024, fc1_b, nullptr, 0, 0, nullptr);
  // fc2 + bias + residual -> out (fp32)
  gemm_bt_kernel<2><<<2048, 256, 0, stream>>>(
      h, w2b, 1024, 1024, 1024, out, 512, fc2_b, x2, 0, 0, nullptr);
}

// Round 9
// 373.279 us; speedup vs baseline: 1.0385x; 1.0385x over previous
//
#include <hip/hip_runtime.h>
#include <cstdint>

typedef unsigned short u16;
typedef __attribute__((ext_vector_type(8))) short s16x8;
typedef __attribute__((ext_vector_type(4))) float f32x4;
typedef __attribute__((ext_vector_type(8))) unsigned short u16x8;
typedef __attribute__((ext_vector_type(4))) unsigned short u16x4;

#define B_ 128
#define T_ 512
#define C_ 512
#define TC 262144

static __device__ __forceinline__ float bf2f(u16 u) {
  union { unsigned int i; float f; } v; v.i = ((unsigned int)u) << 16; return v.f;
}
static __device__ __forceinline__ u16 f2bf(float f) {
  union { float fv; unsigned int i; } v; v.fv = f;
  unsigned int r = (v.i + 0x7FFFu + ((v.i >> 16) & 1u)) >> 16;
  return (u16)r;
}

// x*sigmoid(2z) form of tanh-GELU (passed with absmax 0.031).
static __device__ __forceinline__ float gelu_fast(float x) {
  float x2 = x * x;
  float arg = 1.5957691216057308f * x * fmaf(0.044715f, x2, 1.0f);
  return x / (1.0f + __expf(-arg));
}

#define GLD16(gp, lp) __builtin_amdgcn_global_load_lds( \
    (const __attribute__((address_space(1))) void*)(gp), \
    (__attribute__((address_space(3))) void*)(lp), 16, 0, 0)

// ---------------- LN1 stats: two-stage deterministic reduction ----------------

__global__ __launch_bounds__(256)
void reduce_stats_kernel(const float* __restrict__ X, float2* __restrict__ partials) {
  const int b = blockIdx.y, blk = blockIdx.x, tid = threadIdx.x;
  const float* p = X + (size_t)b * TC + (size_t)blk * 2048 + (size_t)tid * 8;
  f32x4 v0 = *(const f32x4*)p;
  f32x4 v1 = *(const f32x4*)(p + 4);
  float s = 0.f, q = 0.f;
#pragma unroll
  for (int i = 0; i < 4; ++i) { s += v0[i] + v1[i]; q += v0[i] * v0[i] + v1[i] * v1[i]; }
  for (int o = 32; o; o >>= 1) { s += __shfl_down(s, o); q += __shfl_down(q, o); }
  __shared__ float ss[4], qq[4];
  if ((tid & 63) == 0) { ss[tid >> 6] = s; qq[tid >> 6] = q; }
  __syncthreads();
  if (tid == 0)
    partials[(size_t)b * 128 + blk] =
        make_float2(ss[0] + ss[1] + ss[2] + ss[3], qq[0] + qq[1] + qq[2] + qq[3]);
}

__global__ __launch_bounds__(128)
void finalize_stats_kernel(const float2* __restrict__ partials, float2* __restrict__ stats) {
  const int b = blockIdx.x, tid = threadIdx.x;
  float2 v = partials[(size_t)b * 128 + tid];
  float s = v.x, q = v.y;
  for (int o = 32; o; o >>= 1) { s += __shfl_down(s, o); q += __shfl_down(q, o); }
  __shared__ float ss[2], qq[2];
  if ((tid & 63) == 0) { ss[tid >> 6] = s; qq[tid >> 6] = q; }
  __syncthreads();
  if (tid == 0) {
    float sm = ss[0] + ss[1], sq = qq[0] + qq[1];
    float mean = sm * (1.f / (float)TC);
    float var = sq * (1.f / (float)TC) - mean * mean;
    stats[b] = make_float2(mean, rsqrtf(var + 1e-5f));
  }
}

// finalize for 4 partials per batch (TriU-epilogue fused LN2 stats)
__global__ __launch_bounds__(64)
void finalize_stats4_kernel(const float2* __restrict__ partials, float2* __restrict__ stats) {
  const int b = blockIdx.x, tid = threadIdx.x;
  float s = 0.f, q = 0.f;
  if (tid < 4) { float2 v = partials[(size_t)b * 4 + tid]; s = v.x; q = v.y; }
  for (int o = 2; o; o >>= 1) { s += __shfl_down(s, o); q += __shfl_down(q, o); }
  if (tid == 0) {
    float mean = s * (1.f / (float)TC);
    float var = q * (1.f / (float)TC) - mean * mean;
    stats[b] = make_float2(mean, rsqrtf(var + 1e-5f));
  }
}

// --------- LN1 apply + transpose: x^T[b][c][t] = bf16(LN(inputs)) ----------

__global__ __launch_bounds__(256)
void ln1_transpose_kernel(const float* __restrict__ X, const float* __restrict__ W,
                          const float* __restrict__ Bv, const float2* __restrict__ stats,
                          u16* __restrict__ xT) {
  const int b = blockIdx.z;
  const int t0 = blockIdx.y * 64, c0 = blockIdx.x * 64;
  const float2 st = stats[b];
  const float mu = st.x, rs = st.y;
  __shared__ u16 tile[64][72];
  const int tid = threadIdx.x;
  const int rr = tid >> 4;
  const int cc = (tid & 15) * 4;
#pragma unroll
  for (int i = 0; i < 4; ++i) {
    const int lt = i * 16 + rr;
    const size_t wi = (size_t)(t0 + lt) * C_ + c0 + cc;
    f32x4 x = *(const f32x4*)(X + (size_t)b * TC + wi);
    f32x4 w = *(const f32x4*)(W + wi);
    f32x4 bb = *(const f32x4*)(Bv + wi);
#pragma unroll
    for (int j = 0; j < 4; ++j)
      tile[lt][cc + j] = f2bf((x[j] - mu) * rs * w[j] + bb[j]);
  }
  __syncthreads();
  const int c = tid >> 2;
  const int tg = (tid & 3) * 16;
  u16 buf[16];
#pragma unroll
  for (int i = 0; i < 16; ++i) buf[i] = tile[tg + i][c];
  const size_t o = (size_t)b * TC + (size_t)(c0 + c) * T_ + t0 + tg;
  u16x8 o0, o1;
#pragma unroll
  for (int i = 0; i < 8; ++i) { o0[i] = buf[i]; o1[i] = buf[8 + i]; }
  *(u16x8*)(xT + o) = o0;
  *(u16x8*)(xT + o + 8) = o1;
}

// ------------------- LN2 apply (elementwise, bf16 input) -------------------

__global__ __launch_bounds__(256)
void ln2_apply_kernel(const u16* __restrict__ S, const float* __restrict__ W,
                      const float* __restrict__ Bv, const float2* __restrict__ stats,
                      u16* __restrict__ x2) {
  const size_t i = ((size_t)blockIdx.x * 256 + threadIdx.x) * 8;
  const int b = (int)(i >> 18);
  const size_t r = i & (size_t)(TC - 1);
  const float2 st = stats[b];
  const float mu = st.x, rs = st.y;
  u16x8 sv = *(const u16x8*)(S + i);
  f32x4 w0 = *(const f32x4*)(W + r);
  f32x4 w1 = *(const f32x4*)(W + r + 4);
  f32x4 b0 = *(const f32x4*)(Bv + r);
  f32x4 b1 = *(const f32x4*)(Bv + r + 4);
  u16x8 o;
#pragma unroll
  for (int j = 0; j < 4; ++j) {
    o[j]     = f2bf((bf2f(sv[j])     - mu) * rs * w0[j] + b0[j]);
    o[4 + j] = f2bf((bf2f(sv[4 + j]) - mu) * rs * w1[j] + b1[j]);
  }
  *(u16x8*)(x2 + i) = o;
}

// --------------------------- weight conversions ----------------------------

__global__ __launch_bounds__(256)
void cvt_bf16_kernel(const float* __restrict__ X, u16* __restrict__ Y) {
  const size_t i = ((size_t)blockIdx.x * 256 + threadIdx.x) * 4;
  f32x4 v = *(const f32x4*)(X + i);
  u16x4 o;
#pragma unroll
  for (int j = 0; j < 4; ++j) o[j] = f2bf(v[j]);
  *(u16x4*)(Y + i) = o;
}

__global__ __launch_bounds__(256)
void tril_bf16_kernel(const float* __restrict__ Wt, u16* __restrict__ Y) {
  const int i = blockIdx.x * 256 + threadIdx.x;
  const int s = i >> 9, t = i & 511;
  Y[i] = f2bf(t <= s ? Wt[i] : 0.f);
}

// ------- BT-layout MFMA GEMM, 256x256, BK=64, 2-barrier counted-vmcnt -------
// C[m,n] = sum_k A[m,k]*B[n,k].  512 thr = 8 waves (2Mx4N), per-wave 128x64 C.
// LDS: A/B per-K-tile parity dbuf (128 KiB).  Per K-tile:
//   vmcnt(4)->bar1 -> [all 16 A-reads + 4 B(k0)-reads] -> STAGE_B(t+1)
//   -> 32 MFMA(k0) -> 4 B(k1)-reads -> lgkmcnt(0) -> bar2 -> STAGE_A(t+2)
//   -> 32 MFMA(k1)
// Race-proof: B-staging writes the OTHER parity buffer (never conflicts with
// current reads); A-staging targets current parity but is issued only after
// bar2, which every wave reaches with lgkmcnt(0)-complete A-reads.
// NO sched_barrier(0) anywhere (r7's mistake: it pinned regions so swizzled
// LDS addresses were recomputed per phase -> VALUBusy 47%); memory-op order
// around barriers enforced with empty memory-clobber asm only.
// MODE 0: TriU  (z-batched; C=bf16 s = acc+inputs+triu_b[row]; tri K-skip;
//               fused per-block LN2 partial stats)
// MODE 1: fc1   (C=bf16 h = gelu(acc + fc1_b[col]))
// MODE 2: fc2   (C=fp32 out = acc + fc2_b[col] + x2[idx])

template <int MODE>
__global__ __launch_bounds__(512, 1)
void gemm_bt_kernel(const u16* __restrict__ A, const u16* __restrict__ Bm,
                    int K, int lda, int ldb,
                    void* __restrict__ Cp, int ldc,
                    const float* __restrict__ bias,
                    const void* __restrict__ res,
                    long long strideB, long long strideC,
                    float2* __restrict__ stat_part) {
  __shared__ u16 Asb[2 * 16384];   // [parity][256 rows][64 k]  (64 KiB)
  __shared__ u16 Bsb[2 * 16384];   // [parity][256 rows][64 k]  (64 KiB)
  __shared__ float rs_[8], rq_[8];
  const int tid = threadIdx.x;

  // --- XCD-aware bijective remap (nwg % 8 == 0 for all launches) ---
  const int nwg = gridDim.x;
  const int orig = blockIdx.x;
  const int swz = (orig & 7) * (nwg >> 3) + (orig >> 3);
  int bx, by, bz;
  if (MODE == 0) { bz = swz >> 2; by = (swz >> 1) & 1; bx = swz & 1; }
  else if (MODE == 1) { bz = 0; by = swz >> 2; bx = swz & 3; }
  else { bz = 0; by = swz >> 1; bx = swz & 1; }

  const u16* Bp = Bm + (size_t)bz * (size_t)strideB;
  const int m0 = by * 256, n0 = bx * 256;
  int kTiles = K >> 6;
  if (MODE == 0) { const int need = (by + 1) * 4; if (need < kTiles) kTiles = need; }

  const int lane = tid & 63;
  const int wave = tid >> 6;
  const int wm = (wave >> 2) * 128;   // 2 wave-rows of 128
  const int wn = (wave & 3) * 64;     // 4 wave-cols of 64
  const int lr = lane & 15;
  const int kg = lane >> 4;

  f32x4 acc[8][4];
  const f32x4 zero = {0.f, 0.f, 0.f, 0.f};
#pragma unroll
  for (int m = 0; m < 8; ++m)
#pragma unroll
    for (int n = 0; n < 4; ++n) acc[m][n] = zero;

  // One operand tile = 256 rows x 128B = 2048 16B-chunks = 4 GLD16/thread.
  // Source col-chunk XOR (r&7): LDS dest linear, swizzled ds_reads see linear.
  auto STAGE_A = [&](int t) {
    const int k0 = t << 6;
    const int d = (t & 1) * 16384;
#pragma unroll
    for (int p = 0; p < 4; ++p) {
      const int q = p * 512 + tid;
      const int r = q >> 3;
      const int kcs = (q & 7) ^ (r & 7);
      GLD16(A + (size_t)(m0 + r) * lda + k0 + (kcs << 3), &Asb[d + q * 8]);
    }
  };
  auto STAGE_B = [&](int t) {
    const int k0 = t << 6;
    const int d = (t & 1) * 16384;
#pragma unroll
    for (int p = 0; p < 4; ++p) {
      const int q = p * 512 + tid;
      const int r = q >> 3;
      const int kcs = (q & 7) ^ (r & 7);
      GLD16(Bp + (size_t)(n0 + r) * ldb + k0 + (kcs << 3), &Bsb[d + q * 8]);
    }
  };

  // prologue: 12 loads/thread in flight
  STAGE_A(0); STAGE_B(0); STAGE_A(1);

  for (int kt = 0; kt < kTiles; ++kt) {
    const int d = (kt & 1) * 16384;

    // counted wait: newest 4 (A(kt+2-1)) may stay in flight; B(kt),A(kt) done
    if (kt + 1 < kTiles) asm volatile("s_waitcnt vmcnt(4)" ::: "memory");
    else                 asm volatile("s_waitcnt vmcnt(0)" ::: "memory");
    __builtin_amdgcn_s_barrier();
    asm volatile("" ::: "memory");   // keep ds_reads below the barrier

    s16x8 a0[8], a1[8], b0[4], b1[4];
#pragma unroll
    for (int m = 0; m < 8; ++m) {
      const int row = wm + m * 16 + lr;
      const u16* base = &Asb[d + row * 64];
      a0[m] = *(const s16x8*)(base + (((kg)     ^ (row & 7)) << 3));
      a1[m] = *(const s16x8*)(base + (((4 + kg) ^ (row & 7)) << 3));
    }
#pragma unroll
    for (int n = 0; n < 4; ++n) {
      const int row = wn + n * 16 + lr;
      b0[n] = *(const s16x8*)(&Bsb[d + row * 64] + (((kg) ^ (row & 7)) << 3));
    }
    if (kt + 1 < kTiles) STAGE_B(kt + 1);   // other parity buffer: no conflict

    __builtin_amdgcn_s_setprio(1);
#pragma unroll
    for (int m = 0; m < 8; ++m)
#pragma unroll
      for (int n = 0; n < 4; ++n)
        acc[m][n] = __builtin_amdgcn_mfma_f32_16x16x32_bf16(a0[m], b0[n], acc[m][n], 0, 0, 0);
    __builtin_amdgcn_s_setprio(0);

#pragma unroll
    for (int n = 0; n < 4; ++n) {
      const int row = wn + n * 16 + lr;
      b1[n] = *(const s16x8*)(&Bsb[d + row * 64] + (((4 + kg) ^ (row & 7)) << 3));
    }
    asm volatile("s_waitcnt lgkmcnt(0)" ::: "memory");  // all A-reads in regs
    __builtin_amdgcn_s_barrier();                       // every wave's A done
    asm volatile("" ::: "memory");   // keep STAGE_A below the barrier
    if (kt + 2 < kTiles) STAGE_A(kt + 2);   // safe: A-region provably free

    __builtin_amdgcn_s_setprio(1);
#pragma unroll
    for (int m = 0; m < 8; ++m)
#pragma unroll
      for (int n = 0; n < 4; ++n)
        acc[m][n] = __builtin_amdgcn_mfma_f32_16x16x32_bf16(a1[m], b1[n], acc[m][n], 0, 0, 0);
    __builtin_amdgcn_s_setprio(0);
  }

  if (MODE == 0) {
    u16* Cptr = (u16*)Cp + (size_t)bz * (size_t)strideC;
    const float* inp = (const float*)res + (size_t)bz * (size_t)strideC;
    float psum = 0.f, psq = 0.f;
#pragma unroll
    for (int m = 0; m < 8; ++m) {
      const int rb = m0 + wm + m * 16 + kg * 4;
#pragma unroll
      for (int n = 0; n < 4; ++n) {
        const int col = n0 + wn + n * 16 + lr;
#pragma unroll
        for (int j = 0; j < 4; ++j) {
          const size_t idx = (size_t)(rb + j) * ldc + col;
          float v = acc[m][n][j] + inp[idx] + bias[rb + j];
          psum += v; psq += v * v;
          Cptr[idx] = f2bf(v);
        }
      }
    }
    for (int o = 32; o; o >>= 1) { psum += __shfl_down(psum, o); psq += __shfl_down(psq, o); }
    if (lane == 0) { rs_[wave] = psum; rq_[wave] = psq; }
    __syncthreads();
    if (tid == 0) {
      float s = 0.f, q = 0.f;
#pragma unroll
      for (int w = 0; w < 8; ++w) { s += rs_[w]; q += rq_[w]; }
      stat_part[(size_t)bz * 4 + by * 2 + bx] = make_float2(s, q);
    }
  } else if (MODE == 1) {
    u16* Cptr = (u16*)Cp;
#pragma unroll
    for (int m = 0; m < 8; ++m) {
      const int rb = m0 + wm + m * 16 + kg * 4;
#pragma unroll
      for (int n = 0; n < 4; ++n) {
        const int col = n0 + wn + n * 16 + lr;
        const float bs = bias[col];
#pragma unroll
        for (int j = 0; j < 4; ++j) {
          float v = acc[m][n][j] + bs;
          Cptr[(size_t)(rb + j) * ldc + col] = f2bf(gelu_fast(v));
        }
      }
    }
  } else {
    float* Cptr = (float*)Cp;
    const u16* x2p = (const u16*)res;
#pragma unroll
    for (int m = 0; m < 8; ++m) {
      const int rb = m0 + wm + m * 16 + kg * 4;
#pragma unroll
      for (int n = 0; n < 4; ++n) {
        const int col = n0 + wn + n * 16 + lr;
        const float bs = bias[col];
#pragma unroll
        for (int j = 0; j < 4; ++j) {
          const size_t idx = (size_t)(rb + j) * ldc + col;
          Cptr[idx] = acc[m][n][j] + bs + bf2f(x2p[idx]);
        }
      }
    }
  }
}

// -------------------------------- launcher ---------------------------------

extern "C" void kernel_launch(void* const* d_in, const int* in_sizes, int n_in,
                              void* d_out, int out_size, void* d_ws, size_t ws_size,
                              hipStream_t stream) {
  const float* inputs = (const float*)d_in[0];
  const float* ln1_w  = (const float*)d_in[1];
  const float* ln1_b  = (const float*)d_in[2];
  const float* ln2_w  = (const float*)d_in[3];
  const float* ln2_b  = (const float*)d_in[4];
  const float* triu_W = (const float*)d_in[5];
  const float* triu_b = (const float*)d_in[6];
  const float* fc1_W  = (const float*)d_in[7];
  const float* fc1_b  = (const float*)d_in[8];
  const float* fc2_W  = (const float*)d_in[9];
  const float* fc2_b  = (const float*)d_in[10];
  float* out = (float*)d_out;
  (void)in_sizes; (void)n_in; (void)out_size; (void)ws_size;

  char* ws = (char*)d_ws;
  size_t off = 0;
  auto carve = [&](size_t bytes) {
    char* p = ws + off;
    off += (bytes + 255) & ~(size_t)255;
    return p;
  };
  u16* s_bf = (u16*)carve((size_t)B_ * T_ * C_ * 2);   // 67MB bf16 s = mix+inputs+bias
  u16* xT   = (u16*)carve((size_t)B_ * T_ * C_ * 2);   // 67MB; reused as x2
  u16* x2   = xT;
  u16* h    = (u16*)carve((size_t)B_ * T_ * 2 * C_ * 2); // 134MB bf16
  u16* wmb  = (u16*)carve((size_t)T_ * T_ * 2);
  u16* w1b  = (u16*)carve((size_t)2 * C_ * C_ * 2);
  u16* w2b  = (u16*)carve((size_t)C_ * 2 * C_ * 2);
  float2* partials  = (float2*)carve(128 * 128 * sizeof(float2));
  float2* partials2 = (float2*)carve(128 * 4 * sizeof(float2));
  float2* stats1 = (float2*)carve(128 * sizeof(float2));
  float2* stats2 = (float2*)carve(128 * sizeof(float2));

  // LN1 stats
  reduce_stats_kernel<<<dim3(128, 128), 256, 0, stream>>>(inputs, partials);
  finalize_stats_kernel<<<128, 128, 0, stream>>>(partials, stats1);
  // LN1 apply + transpose -> xT (bf16)
  ln1_transpose_kernel<<<dim3(8, 8, 128), 256, 0, stream>>>(inputs, ln1_w, ln1_b, stats1, xT);
  // weight prep
  tril_bf16_kernel<<<1024, 256, 0, stream>>>(triu_W, wmb);
  cvt_bf16_kernel<<<512, 256, 0, stream>>>(fc1_W, w1b);
  cvt_bf16_kernel<<<512, 256, 0, stream>>>(fc2_W, w2b);
  // TriU mix: s = tril(W) @ x + triu_b + inputs (bf16 out) + fused LN2 partial stats
  gemm_bt_kernel<0><<<512, 512, 0, stream>>>(
      wmb, xT, 512, 512, 512, s_bf, 512, triu_b, inputs, (long long)TC, (long long)TC, partials2);
  finalize_stats4_kernel<<<128, 64, 0, stream>>>(partials2, stats2);
  // LN2 apply -> x2 (bf16)
  ln2_apply_kernel<<<16384, 256, 0, stream>>>(s_bf, ln2_w, ln2_b, stats2, x2);
  // fc1 + GELU -> h (bf16)
  gemm_bt_kernel<1><<<1024, 512, 0, stream>>>(
      x2, w1b, 512, 512, 512, h, 1024, fc1_b, nullptr, 0, 0, nullptr);
  // fc2 + bias + residual -> out (fp32)
  gemm_bt_kernel<2><<<512, 512, 0, stream>>>(
      h, w2b, 1024, 1024, 1024, out, 512, fc2_b, x2, 0, 0, nullptr);
}